// Round 16
// baseline (266.183 us; speedup 1.0000x reference)
//
#include <hip/hip_runtime.h>
#include <hip/hip_bf16.h>
#include <stdint.h>

#define NN 32768
#define HH 256

typedef short bf16x8 __attribute__((ext_vector_type(8)));
typedef float f32x4 __attribute__((ext_vector_type(4)));
typedef unsigned short ushort_t;
typedef unsigned short ushort8_t __attribute__((ext_vector_type(8)));

__device__ __forceinline__ ushort_t f2bf(float f) {
  union { float f; unsigned u; } v; v.f = f;
  unsigned u = v.u;
  unsigned r = (u + 0x7FFFu + ((u >> 16) & 1u)) >> 16;  // RNE (cold paths)
  return (ushort_t)r;
}
__device__ __forceinline__ float bf2f(ushort_t h) {
  union { unsigned u; float f; } v; v.u = ((unsigned)h) << 16;
  return v.f;
}
__device__ __forceinline__ unsigned cvt_pk(float lo, float hi) {
  unsigned r;
  asm("v_cvt_pk_bf16_f32 %0, %1, %2" : "=v"(r) : "v"(lo), "v"(hi));
  return r;
}
__device__ __forceinline__ float sigmoidf_(float x) {
  float e = __builtin_amdgcn_exp2f(-1.4426950408889634f * x);
  return __builtin_amdgcn_rcpf(1.f + e);
}
__device__ __forceinline__ float tanhf_(float x) {
  float ax = fminf(fabsf(x), 15.f);
  float e = __builtin_amdgcn_exp2f(2.8853900817779268f * ax);
  float t = (e - 1.f) * __builtin_amdgcn_rcpf(e + 1.f);
  return copysignf(t, x);
}
// XOR swizzle within a 256-elem row
__device__ __forceinline__ int swz(int row, int col) {
  return row * 256 + ((((col >> 3) ^ (row & 7)) << 3) | (col & 7));
}
// XOR swizzle within a 512-elem row
__device__ __forceinline__ int swzK(int row, int col) {
  return row * 512 + ((((col >> 3) ^ (row & 7)) << 3) | (col & 7));
}

// ---------------- prep: weights -> bf16, transposed [verified R7/R9/R11] -----
__global__ void k_prep(const float* __restrict__ W_iou, const float* __restrict__ W_fin,
                       const float* __restrict__ W_f, const float* __restrict__ W_aggr,
                       ushort_t* __restrict__ WfT, ushort_t* __restrict__ WfinT,
                       ushort_t* __restrict__ WcatKT) {
  int tid = blockIdx.x * 256 + threadIdx.x;
  if (tid < 65536) {
    int n = tid >> 8, k = tid & 255;
    WfT[tid] = f2bf(W_f[k * 256 + n]);
  } else if (tid < 131072) {
    int t2 = tid - 65536; int n = t2 >> 8, k = t2 & 255;
    WfinT[t2] = f2bf(W_fin[k * 256 + n]);
  } else {
    int t3 = tid - 131072;            // < 393216
    int n = t3 >> 9, k = t3 & 511;
    float v = (k < 256) ? W_aggr[k * 768 + n] : W_iou[(k - 256) * 768 + n];
    WcatKT[t3] = f2bf(v);
  }
}

// ---------------- k_fin [verified R7/R9/R11; x_bf store deleted] -------------
__global__ __launch_bounds__(512, 4) void k_fin(
    const float* __restrict__ x, const ushort_t* __restrict__ WfinT,
    const float* __restrict__ b_fin,
    ushort_t* __restrict__ f_out) {
  __shared__ __align__(16) ushort_t As[64 * 256];   // 32 KB
  const int tid = threadIdx.x;
  const size_t blk = blockIdx.x;                    // 64 rows
  const int lane = tid & 63, wv = tid >> 6;
  const int g = lane >> 4, r = lane & 15;
  const int mb = wv * 32;

  bf16x8 wfrag[2][8];
#pragma unroll
  for (int ct = 0; ct < 2; ++ct)
#pragma unroll
    for (int kb = 0; kb < 8; ++kb)
      wfrag[ct][kb] = *(const bf16x8*)&WfinT[(mb + ct * 16 + r) * 256 + kb * 32 + g * 8];
  float bias[2] = { b_fin[mb + r], b_fin[mb + 16 + r] };

  const int rowgrp = tid >> 5, seg8 = tid & 31;
  const float* src = x + ((size_t)blk * 64 + rowgrp * 4) * 256 + seg8 * 8;
#pragma unroll
  for (int rr = 0; rr < 4; ++rr) {
    float4 va = *(const float4*)(src + (size_t)rr * 256);
    float4 vb = *(const float4*)(src + (size_t)rr * 256 + 4);
    uint4 p = { cvt_pk(va.x, va.y), cvt_pk(va.z, va.w),
                cvt_pk(vb.x, vb.y), cvt_pk(vb.z, vb.w) };
    *(uint4*)&As[swz(rowgrp * 4 + rr, seg8 * 8)] = p;
  }
  __syncthreads();

#pragma unroll
  for (int p = 0; p < 2; ++p) {
    f32x4 acc[2][2] = {};
#pragma unroll
    for (int kb = 0; kb < 8; ++kb) {
      const int kc = kb * 32 + g * 8;
      bf16x8 a0 = *(const bf16x8*)&As[swz(p * 32 + r, kc)];
      bf16x8 a1 = *(const bf16x8*)&As[swz(p * 32 + 16 + r, kc)];
      acc[0][0] = __builtin_amdgcn_mfma_f32_16x16x32_bf16(a0, wfrag[0][kb], acc[0][0], 0, 0, 0);
      acc[0][1] = __builtin_amdgcn_mfma_f32_16x16x32_bf16(a0, wfrag[1][kb], acc[0][1], 0, 0, 0);
      acc[1][0] = __builtin_amdgcn_mfma_f32_16x16x32_bf16(a1, wfrag[0][kb], acc[1][0], 0, 0, 0);
      acc[1][1] = __builtin_amdgcn_mfma_f32_16x16x32_bf16(a1, wfrag[1][kb], acc[1][1], 0, 0, 0);
    }
#pragma unroll
    for (int rt = 0; rt < 2; ++rt)
#pragma unroll
      for (int ct = 0; ct < 2; ++ct)
#pragma unroll
        for (int i = 0; i < 4; ++i) {
          float v = acc[rt][ct][i] + bias[ct];
          float v2 = __shfl_xor(v, 1);
          if ((r & 1) == 0) {
            size_t row = blk * 64 + p * 32 + rt * 16 + g * 4 + i;
            *(unsigned*)&f_out[row * 256 + mb + ct * 16 + r] = cvt_pk(v, v2);
          }
        }
  }
}

// ---------------- k_fgate [R11 verbatim — verified 159 us, best of 6 variants]
__global__ __launch_bounds__(1024, 4) void k_fgate(
    const float* __restrict__ nh, const float* __restrict__ nc,
    const ushort_t* __restrict__ WfT, const float* __restrict__ b_f,
    const ushort_t* __restrict__ f_in,
    float* __restrict__ cau_out, ushort_t* __restrict__ hsum_out) {
  __shared__ __align__(16) ushort_t As[64 * 256];   // 32 KB
  const int tid = threadIdx.x;
  const size_t blk = blockIdx.x;                    // 64 rows per block
  const int lane = tid & 63, wv = tid >> 6;         // wv 0..15
  const int g = lane >> 4, r = lane & 15;
  const int col = wv * 16 + r;                      // lane's output col

  // W_f^T fragments (B-operand)
  bf16x8 wfrag[8];
#pragma unroll
  for (int kb = 0; kb < 8; ++kb)
    wfrag[kb] = *(const bf16x8*)&WfT[col * 256 + kb * 32 + g * 8];
  const float bias = b_f[col];

  // staging + fused f32 hsum: waves 0-7, wave = node, lane = col-quad
  if (wv < 8) {
    const float* src = nh + (blk * 64 + wv * 8) * 256 + lane * 4;
    float s0 = 0.f, s1 = 0.f, s2 = 0.f, s3 = 0.f;
#pragma unroll
    for (int bb = 0; bb < 2; ++bb) {
      float4 v[4];
#pragma unroll
      for (int c = 0; c < 4; ++c) v[c] = *(const float4*)(src + (size_t)(bb * 4 + c) * 256);
#pragma unroll
      for (int c = 0; c < 4; ++c) {
        uint2 p = { cvt_pk(v[c].x, v[c].y), cvt_pk(v[c].z, v[c].w) };
        *(uint2*)&As[swz(wv * 8 + bb * 4 + c, lane * 4)] = p;
        s0 += v[c].x; s1 += v[c].y; s2 += v[c].z; s3 += v[c].w;
      }
    }
    uint2 o = { cvt_pk(s0, s1), cvt_pk(s2, s3) };
    *(uint2*)&hsum_out[(blk * 8 + wv) * 256 + lane * 4] = o;
  }
  __syncthreads();

  // prefetch nc + f_in
  float ncv[4][4];
  float fvv[4];
#pragma unroll
  for (int rt = 0; rt < 4; ++rt) {
    const int nodeL = rt * 2 + (g >> 1);
    fvv[rt] = bf2f(f_in[(blk * 8 + nodeL) * 256 + col]);
    const float* ncp = nc + (blk * 64 + rt * 16 + g * 4) * 256 + col;
#pragma unroll
    for (int i = 0; i < 4; ++i) ncv[rt][i] = ncp[(size_t)i * 256];
  }

  // MFMA: C[64 rows][16 cols] per wave
  f32x4 acc[4] = {};
#pragma unroll
  for (int kb = 0; kb < 8; ++kb) {
    const int kc = kb * 32 + g * 8;
#pragma unroll
    for (int rt = 0; rt < 4; ++rt) {
      bf16x8 a = *(const bf16x8*)&As[swz(rt * 16 + r, kc)];
      acc[rt] = __builtin_amdgcn_mfma_f32_16x16x32_bf16(a, wfrag[kb], acc[rt], 0, 0, 0);
    }
  }

  // epilogue: gates + f*nc + in-lane child reduce + 1 shfl; f32 store
#pragma unroll
  for (int rt = 0; rt < 4; ++rt) {
    const int nodeL = rt * 2 + (g >> 1);
    const size_t nodeG = blk * 8 + nodeL;
    const float base = bias + fvv[rt];
    float s = 0.f;
#pragma unroll
    for (int i = 0; i < 4; ++i)
      s += sigmoidf_(acc[rt][i] + base) * ncv[rt][i];
    s += __shfl_xor(s, 16);
    if ((g & 1) == 0)
      cau_out[nodeG * 256 + col] = s;
  }
}

// ---------------- k_final v4 [verified R12]: 64 nodes/block, x from f32 ------
// c_aggr read inline from out_c (f32, same-thread RAW only).
__global__ __launch_bounds__(512, 2) void k_final(
    const ushort_t* __restrict__ hsum, const float* __restrict__ x,
    const ushort_t* __restrict__ WcatKT,
    const float* __restrict__ b_iou, const float* __restrict__ b_aggr,
    float* out_h, float* out_c) {
  __shared__ __align__(16) ushort_t As[64 * 512];   // 64 KB (A = [hsum | x])
  const int tid = threadIdx.x;
  const size_t blk = blockIdx.x;                    // 64 nodes
  const int lane = tid & 63, wv = tid >> 6;
  const int g = lane >> 4, r = lane & 15;

  // stage A: 64 rows x 512 cols bf16; 8 threads/row, 8 x 16B each
  {
    int row = tid >> 3, seg = tid & 7;
    const size_t nodeG = blk * 64 + row;
#pragma unroll
    for (int jj = 0; jj < 8; ++jj) {
      int col = seg * 64 + jj * 8;
      ushort8_t v;
      if (col < 256) {
        v = *(const ushort8_t*)&hsum[nodeG * 256 + col];
      } else {
        float4 a = *(const float4*)&x[nodeG * 256 + col - 256];
        float4 b = *(const float4*)&x[nodeG * 256 + col - 256 + 4];
        uint4 p = { cvt_pk(a.x, a.y), cvt_pk(a.z, a.w),
                    cvt_pk(b.x, b.y), cvt_pk(b.z, b.w) };
        v = *(ushort8_t*)&p;
      }
      *(ushort8_t*)&As[swzK(row, col)] = v;
    }
  }
  float biasv[3][2];
#pragma unroll
  for (int p = 0; p < 3; ++p)
#pragma unroll
    for (int j = 0; j < 2; ++j) {
      int c = p * 256 + wv * 32 + j * 16 + r;
      biasv[p][j] = b_iou[c] + b_aggr[c];
    }
  __syncthreads();

  f32x4 acc[3][4][2] = {};   // [p][rt][j]  (96 VGPR)
#pragma unroll
  for (int q = 0; q < 8; ++q) {
    bf16x8 wf[3][2][2];
#pragma unroll
    for (int p = 0; p < 3; ++p)
#pragma unroll
      for (int j = 0; j < 2; ++j)
#pragma unroll
        for (int kb = 0; kb < 2; ++kb)
          wf[p][j][kb] = *(const bf16x8*)&WcatKT[
              (size_t)(p * 256 + wv * 32 + j * 16 + r) * 512 + q * 64 + kb * 32 + g * 8];
#pragma unroll
    for (int kb = 0; kb < 2; ++kb) {
      const int kc = q * 64 + kb * 32 + g * 8;
#pragma unroll
      for (int rt = 0; rt < 4; ++rt) {
        bf16x8 a = *(const bf16x8*)&As[swzK(rt * 16 + r, kc)];
#pragma unroll
        for (int p = 0; p < 3; ++p)
#pragma unroll
          for (int j = 0; j < 2; ++j)
            acc[p][rt][j] = __builtin_amdgcn_mfma_f32_16x16x32_bf16(a, wf[p][j][kb], acc[p][rt][j], 0, 0, 0);
      }
    }
  }

#pragma unroll
  for (int rt = 0; rt < 4; ++rt)
#pragma unroll
    for (int j = 0; j < 2; ++j)
#pragma unroll
      for (int i = 0; i < 4; ++i) {
        int nl = rt * 16 + g * 4 + i;
        int col = wv * 32 + j * 16 + r;
        size_t node = blk * 64 + nl;
        float iv = acc[0][rt][j][i] + biasv[0][j];
        float ov = acc[1][rt][j][i] + biasv[1][j];
        float uv = acc[2][rt][j][i] + biasv[2][j];
        float ca = out_c[node * 256 + col];          // f32 c_aggr (same thread)
        float cn = sigmoidf_(iv) * tanhf_(uv) + ca;
        out_c[node * 256 + col] = cn;
        out_h[node * 256 + col] = sigmoidf_(ov) * tanhf_(cn);
      }
}

extern "C" void kernel_launch(void* const* d_in, const int* in_sizes, int n_in,
                              void* d_out, int out_size, void* d_ws, size_t ws_size,
                              hipStream_t stream) {
  const float* x      = (const float*)d_in[0];
  const float* nh     = (const float*)d_in[1];
  const float* nc     = (const float*)d_in[2];
  const float* W_iou  = (const float*)d_in[3];
  const float* b_iou  = (const float*)d_in[4];
  const float* W_fin  = (const float*)d_in[5];
  const float* b_fin  = (const float*)d_in[6];
  const float* W_f    = (const float*)d_in[7];
  const float* b_f    = (const float*)d_in[8];
  const float* W_aggr = (const float*)d_in[9];
  const float* b_aggr = (const float*)d_in[10];

  char* ws = (char*)d_ws;
  ushort_t* WfT    = (ushort_t*)ws;                               // 128 KB
  ushort_t* WfinT  = (ushort_t*)(ws + (128 << 10));               // 128 KB
  ushort_t* WcatKT = (ushort_t*)(ws + (256 << 10));               // 768 KB
  ushort_t* f_in   = (ushort_t*)(ws + (1 << 20));                 // 16 MB
  ushort_t* hsum   = (ushort_t*)(ws + (17 << 20));                // 16 MB

  float* out_h = (float*)d_out;
  float* out_c = out_h + (size_t)NN * HH;

  k_prep<<<2048, 256, 0, stream>>>(W_iou, W_fin, W_f, W_aggr, WfT, WfinT, WcatKT);
  k_fin<<<512, 512, 0, stream>>>(x, WfinT, b_fin, f_in);
  k_fgate<<<4096, 1024, 0, stream>>>(nh, nc, WfT, b_f, f_in, out_c, hsum);
  k_final<<<512, 512, 0, stream>>>(hsum, x, WcatKT, b_iou, b_aggr, out_h, out_c);
}

// Round 17
// 263.055 us; speedup vs baseline: 1.0119x; 1.0119x over previous
//
#include <hip/hip_runtime.h>
#include <hip/hip_bf16.h>
#include <stdint.h>

#define NN 32768
#define HH 256

typedef short bf16x8 __attribute__((ext_vector_type(8)));
typedef float f32x4 __attribute__((ext_vector_type(4)));
typedef unsigned short ushort_t;
typedef unsigned short ushort8_t __attribute__((ext_vector_type(8)));

__device__ __forceinline__ ushort_t f2bf(float f) {
  union { float f; unsigned u; } v; v.f = f;
  unsigned u = v.u;
  unsigned r = (u + 0x7FFFu + ((u >> 16) & 1u)) >> 16;  // RNE (cold paths)
  return (ushort_t)r;
}
__device__ __forceinline__ float bf2f(ushort_t h) {
  union { unsigned u; float f; } v; v.u = ((unsigned)h) << 16;
  return v.f;
}
__device__ __forceinline__ unsigned cvt_pk(float lo, float hi) {
  unsigned r;
  asm("v_cvt_pk_bf16_f32 %0, %1, %2" : "=v"(r) : "v"(lo), "v"(hi));
  return r;
}
__device__ __forceinline__ float sigmoidf_(float x) {
  float e = __builtin_amdgcn_exp2f(-1.4426950408889634f * x);
  return __builtin_amdgcn_rcpf(1.f + e);
}
__device__ __forceinline__ float tanhf_(float x) {
  float ax = fminf(fabsf(x), 15.f);
  float e = __builtin_amdgcn_exp2f(2.8853900817779268f * ax);
  float t = (e - 1.f) * __builtin_amdgcn_rcpf(e + 1.f);
  return copysignf(t, x);
}
// XOR swizzle within a 256-elem row
__device__ __forceinline__ int swz(int row, int col) {
  return row * 256 + ((((col >> 3) ^ (row & 7)) << 3) | (col & 7));
}
// XOR swizzle within a 512-elem row
__device__ __forceinline__ int swzK(int row, int col) {
  return row * 512 + ((((col >> 3) ^ (row & 7)) << 3) | (col & 7));
}

// ---------------- prep: weights -> bf16, transposed [verified R7/R9/R11] -----
__global__ void k_prep(const float* __restrict__ W_iou, const float* __restrict__ W_fin,
                       const float* __restrict__ W_f, const float* __restrict__ W_aggr,
                       ushort_t* __restrict__ WfT, ushort_t* __restrict__ WfinT,
                       ushort_t* __restrict__ WcatKT) {
  int tid = blockIdx.x * 256 + threadIdx.x;
  if (tid < 65536) {
    int n = tid >> 8, k = tid & 255;
    WfT[tid] = f2bf(W_f[k * 256 + n]);
  } else if (tid < 131072) {
    int t2 = tid - 65536; int n = t2 >> 8, k = t2 & 255;
    WfinT[t2] = f2bf(W_fin[k * 256 + n]);
  } else {
    int t3 = tid - 131072;            // < 393216
    int n = t3 >> 9, k = t3 & 511;
    float v = (k < 256) ? W_aggr[k * 768 + n] : W_iou[(k - 256) * 768 + n];
    WcatKT[t3] = f2bf(v);
  }
}

// ---------------- k_fin [verified R7/R9/R11] ---------------------------------
__global__ __launch_bounds__(512, 4) void k_fin(
    const float* __restrict__ x, const ushort_t* __restrict__ WfinT,
    const float* __restrict__ b_fin,
    ushort_t* __restrict__ f_out, ushort_t* __restrict__ xbf_out) {
  __shared__ __align__(16) ushort_t As[64 * 256];   // 32 KB
  const int tid = threadIdx.x;
  const size_t blk = blockIdx.x;                    // 64 rows
  const int lane = tid & 63, wv = tid >> 6;
  const int g = lane >> 4, r = lane & 15;
  const int mb = wv * 32;

  bf16x8 wfrag[2][8];
#pragma unroll
  for (int ct = 0; ct < 2; ++ct)
#pragma unroll
    for (int kb = 0; kb < 8; ++kb)
      wfrag[ct][kb] = *(const bf16x8*)&WfinT[(mb + ct * 16 + r) * 256 + kb * 32 + g * 8];
  float bias[2] = { b_fin[mb + r], b_fin[mb + 16 + r] };

  const int rowgrp = tid >> 5, seg8 = tid & 31;
  const float* src = x + ((size_t)blk * 64 + rowgrp * 4) * 256 + seg8 * 8;
#pragma unroll
  for (int rr = 0; rr < 4; ++rr) {
    float4 va = *(const float4*)(src + (size_t)rr * 256);
    float4 vb = *(const float4*)(src + (size_t)rr * 256 + 4);
    uint4 p = { cvt_pk(va.x, va.y), cvt_pk(va.z, va.w),
                cvt_pk(vb.x, vb.y), cvt_pk(vb.z, vb.w) };
    *(uint4*)&As[swz(rowgrp * 4 + rr, seg8 * 8)] = p;
    *(uint4*)&xbf_out[((size_t)blk * 64 + rowgrp * 4 + rr) * 256 + seg8 * 8] = p;
  }
  __syncthreads();

#pragma unroll
  for (int p = 0; p < 2; ++p) {
    f32x4 acc[2][2] = {};
#pragma unroll
    for (int kb = 0; kb < 8; ++kb) {
      const int kc = kb * 32 + g * 8;
      bf16x8 a0 = *(const bf16x8*)&As[swz(p * 32 + r, kc)];
      bf16x8 a1 = *(const bf16x8*)&As[swz(p * 32 + 16 + r, kc)];
      acc[0][0] = __builtin_amdgcn_mfma_f32_16x16x32_bf16(a0, wfrag[0][kb], acc[0][0], 0, 0, 0);
      acc[0][1] = __builtin_amdgcn_mfma_f32_16x16x32_bf16(a0, wfrag[1][kb], acc[0][1], 0, 0, 0);
      acc[1][0] = __builtin_amdgcn_mfma_f32_16x16x32_bf16(a1, wfrag[0][kb], acc[1][0], 0, 0, 0);
      acc[1][1] = __builtin_amdgcn_mfma_f32_16x16x32_bf16(a1, wfrag[1][kb], acc[1][1], 0, 0, 0);
    }
#pragma unroll
    for (int rt = 0; rt < 2; ++rt)
#pragma unroll
      for (int ct = 0; ct < 2; ++ct)
#pragma unroll
        for (int i = 0; i < 4; ++i) {
          float v = acc[rt][ct][i] + bias[ct];
          float v2 = __shfl_xor(v, 1);
          if ((r & 1) == 0) {
            size_t row = blk * 64 + p * 32 + rt * 16 + g * 4 + i;
            *(unsigned*)&f_out[row * 256 + mb + ct * 16 + r] = cvt_pk(v, v2);
          }
        }
  }
}

// ---------------- k_fgate [R11 verbatim — verified 159 us, best of 7 variants]
// 16 waves, 16 cols/wave; wfrag preloaded PRE-barrier (residency invariant);
// waves 0-7 stage nh + in-register f32 hsum; f32 c_aggr store into out_c.
__global__ __launch_bounds__(1024, 4) void k_fgate(
    const float* __restrict__ nh, const float* __restrict__ nc,
    const ushort_t* __restrict__ WfT, const float* __restrict__ b_f,
    const ushort_t* __restrict__ f_in,
    float* __restrict__ cau_out, ushort_t* __restrict__ hsum_out) {
  __shared__ __align__(16) ushort_t As[64 * 256];   // 32 KB
  const int tid = threadIdx.x;
  const size_t blk = blockIdx.x;                    // 64 rows per block
  const int lane = tid & 63, wv = tid >> 6;         // wv 0..15
  const int g = lane >> 4, r = lane & 15;
  const int col = wv * 16 + r;                      // lane's output col

  // W_f^T fragments (B-operand)
  bf16x8 wfrag[8];
#pragma unroll
  for (int kb = 0; kb < 8; ++kb)
    wfrag[kb] = *(const bf16x8*)&WfT[col * 256 + kb * 32 + g * 8];
  const float bias = b_f[col];

  // staging + fused f32 hsum: waves 0-7, wave = node, lane = col-quad
  if (wv < 8) {
    const float* src = nh + (blk * 64 + wv * 8) * 256 + lane * 4;
    float s0 = 0.f, s1 = 0.f, s2 = 0.f, s3 = 0.f;
#pragma unroll
    for (int bb = 0; bb < 2; ++bb) {
      float4 v[4];
#pragma unroll
      for (int c = 0; c < 4; ++c) v[c] = *(const float4*)(src + (size_t)(bb * 4 + c) * 256);
#pragma unroll
      for (int c = 0; c < 4; ++c) {
        uint2 p = { cvt_pk(v[c].x, v[c].y), cvt_pk(v[c].z, v[c].w) };
        *(uint2*)&As[swz(wv * 8 + bb * 4 + c, lane * 4)] = p;
        s0 += v[c].x; s1 += v[c].y; s2 += v[c].z; s3 += v[c].w;
      }
    }
    uint2 o = { cvt_pk(s0, s1), cvt_pk(s2, s3) };
    *(uint2*)&hsum_out[(blk * 8 + wv) * 256 + lane * 4] = o;
  }
  __syncthreads();

  // prefetch nc + f_in
  float ncv[4][4];
  float fvv[4];
#pragma unroll
  for (int rt = 0; rt < 4; ++rt) {
    const int nodeL = rt * 2 + (g >> 1);
    fvv[rt] = bf2f(f_in[(blk * 8 + nodeL) * 256 + col]);
    const float* ncp = nc + (blk * 64 + rt * 16 + g * 4) * 256 + col;
#pragma unroll
    for (int i = 0; i < 4; ++i) ncv[rt][i] = ncp[(size_t)i * 256];
  }

  // MFMA: C[64 rows][16 cols] per wave
  f32x4 acc[4] = {};
#pragma unroll
  for (int kb = 0; kb < 8; ++kb) {
    const int kc = kb * 32 + g * 8;
#pragma unroll
    for (int rt = 0; rt < 4; ++rt) {
      bf16x8 a = *(const bf16x8*)&As[swz(rt * 16 + r, kc)];
      acc[rt] = __builtin_amdgcn_mfma_f32_16x16x32_bf16(a, wfrag[kb], acc[rt], 0, 0, 0);
    }
  }

  // epilogue: gates + f*nc + in-lane child reduce + 1 shfl; f32 store
#pragma unroll
  for (int rt = 0; rt < 4; ++rt) {
    const int nodeL = rt * 2 + (g >> 1);
    const size_t nodeG = blk * 8 + nodeL;
    const float base = bias + fvv[rt];
    float s = 0.f;
#pragma unroll
    for (int i = 0; i < 4; ++i)
      s += sigmoidf_(acc[rt][i] + base) * ncv[rt][i];
    s += __shfl_xor(s, 16);
    if ((g & 1) == 0)
      cau_out[nodeG * 256 + col] = s;
  }
}

// ---------------- k_final v3 [verified R11]: 64 nodes/block ------------------
// c_aggr read inline from out_c (f32, same-thread RAW only).
__global__ __launch_bounds__(512, 2) void k_final(
    const ushort_t* __restrict__ hsum, const ushort_t* __restrict__ xbf,
    const ushort_t* __restrict__ WcatKT,
    const float* __restrict__ b_iou, const float* __restrict__ b_aggr,
    float* out_h, float* out_c) {
  __shared__ __align__(16) ushort_t As[64 * 512];   // 64 KB (A = [hsum | x])
  const int tid = threadIdx.x;
  const size_t blk = blockIdx.x;                    // 64 nodes
  const int lane = tid & 63, wv = tid >> 6;
  const int g = lane >> 4, r = lane & 15;

  // stage A: 64 rows x 512 cols bf16; 8 threads/row, 8 x 16B each
  {
    int row = tid >> 3, seg = tid & 7;
    const size_t nodeG = blk * 64 + row;
#pragma unroll
    for (int jj = 0; jj < 8; ++jj) {
      int col = seg * 64 + jj * 8;
      ushort8_t v = (col < 256)
          ? *(const ushort8_t*)&hsum[nodeG * 256 + col]
          : *(const ushort8_t*)&xbf[nodeG * 256 + col - 256];
      *(ushort8_t*)&As[swzK(row, col)] = v;
    }
  }
  float biasv[3][2];
#pragma unroll
  for (int p = 0; p < 3; ++p)
#pragma unroll
    for (int j = 0; j < 2; ++j) {
      int c = p * 256 + wv * 32 + j * 16 + r;
      biasv[p][j] = b_iou[c] + b_aggr[c];
    }
  __syncthreads();

  f32x4 acc[3][4][2] = {};   // [p][rt][j]  (96 VGPR)
#pragma unroll
  for (int q = 0; q < 8; ++q) {
    bf16x8 wf[3][2][2];
#pragma unroll
    for (int p = 0; p < 3; ++p)
#pragma unroll
      for (int j = 0; j < 2; ++j)
#pragma unroll
        for (int kb = 0; kb < 2; ++kb)
          wf[p][j][kb] = *(const bf16x8*)&WcatKT[
              (size_t)(p * 256 + wv * 32 + j * 16 + r) * 512 + q * 64 + kb * 32 + g * 8];
#pragma unroll
    for (int kb = 0; kb < 2; ++kb) {
      const int kc = q * 64 + kb * 32 + g * 8;
#pragma unroll
      for (int rt = 0; rt < 4; ++rt) {
        bf16x8 a = *(const bf16x8*)&As[swzK(rt * 16 + r, kc)];
#pragma unroll
        for (int p = 0; p < 3; ++p)
#pragma unroll
          for (int j = 0; j < 2; ++j)
            acc[p][rt][j] = __builtin_amdgcn_mfma_f32_16x16x32_bf16(a, wf[p][j][kb], acc[p][rt][j], 0, 0, 0);
      }
    }
  }

#pragma unroll
  for (int rt = 0; rt < 4; ++rt)
#pragma unroll
    for (int j = 0; j < 2; ++j)
#pragma unroll
      for (int i = 0; i < 4; ++i) {
        int nl = rt * 16 + g * 4 + i;
        int col = wv * 32 + j * 16 + r;
        size_t node = blk * 64 + nl;
        float iv = acc[0][rt][j][i] + biasv[0][j];
        float ov = acc[1][rt][j][i] + biasv[1][j];
        float uv = acc[2][rt][j][i] + biasv[2][j];
        float ca = out_c[node * 256 + col];          // f32 c_aggr (same thread)
        float cn = sigmoidf_(iv) * tanhf_(uv) + ca;
        out_c[node * 256 + col] = cn;
        out_h[node * 256 + col] = sigmoidf_(ov) * tanhf_(cn);
      }
}

extern "C" void kernel_launch(void* const* d_in, const int* in_sizes, int n_in,
                              void* d_out, int out_size, void* d_ws, size_t ws_size,
                              hipStream_t stream) {
  const float* x      = (const float*)d_in[0];
  const float* nh     = (const float*)d_in[1];
  const float* nc     = (const float*)d_in[2];
  const float* W_iou  = (const float*)d_in[3];
  const float* b_iou  = (const float*)d_in[4];
  const float* W_fin  = (const float*)d_in[5];
  const float* b_fin  = (const float*)d_in[6];
  const float* W_f    = (const float*)d_in[7];
  const float* b_f    = (const float*)d_in[8];
  const float* W_aggr = (const float*)d_in[9];
  const float* b_aggr = (const float*)d_in[10];

  char* ws = (char*)d_ws;
  ushort_t* WfT    = (ushort_t*)ws;                               // 128 KB
  ushort_t* WfinT  = (ushort_t*)(ws + (128 << 10));               // 128 KB
  ushort_t* WcatKT = (ushort_t*)(ws + (256 << 10));               // 768 KB
  ushort_t* f_in   = (ushort_t*)(ws + (1 << 20));                 // 16 MB
  ushort_t* hsum   = (ushort_t*)(ws + (17 << 20));                // 16 MB
  ushort_t* x_bf   = (ushort_t*)(ws + (33 << 20));                // 16 MB

  float* out_h = (float*)d_out;
  float* out_c = out_h + (size_t)NN * HH;

  k_prep<<<2048, 256, 0, stream>>>(W_iou, W_fin, W_f, W_aggr, WfT, WfinT, WcatKT);
  k_fin<<<512, 512, 0, stream>>>(x, WfinT, b_fin, f_in, x_bf);
  k_fgate<<<4096, 1024, 0, stream>>>(nh, nc, WfT, b_f, f_in, out_c, hsum);
  k_final<<<512, 512, 0, stream>>>(hsum, x_bf, WcatKT, b_iou, b_aggr, out_h, out_c);
}

// Round 18
// 253.756 us; speedup vs baseline: 1.0490x; 1.0366x over previous
//
#include <hip/hip_runtime.h>
#include <hip/hip_bf16.h>
#include <stdint.h>

#define NN 32768
#define HH 256

typedef short bf16x8 __attribute__((ext_vector_type(8)));
typedef float f32x4 __attribute__((ext_vector_type(4)));
typedef unsigned short ushort_t;
typedef unsigned short ushort8_t __attribute__((ext_vector_type(8)));

__device__ __forceinline__ ushort_t f2bf(float f) {
  union { float f; unsigned u; } v; v.f = f;
  unsigned u = v.u;
  unsigned r = (u + 0x7FFFu + ((u >> 16) & 1u)) >> 16;  // RNE (cold paths)
  return (ushort_t)r;
}
__device__ __forceinline__ float bf2f(ushort_t h) {
  union { unsigned u; float f; } v; v.u = ((unsigned)h) << 16;
  return v.f;
}
__device__ __forceinline__ unsigned cvt_pk(float lo, float hi) {
  unsigned r;
  asm("v_cvt_pk_bf16_f32 %0, %1, %2" : "=v"(r) : "v"(lo), "v"(hi));
  return r;
}
__device__ __forceinline__ float sigmoidf_(float x) {
  float e = __builtin_amdgcn_exp2f(-1.4426950408889634f * x);
  return __builtin_amdgcn_rcpf(1.f + e);
}
__device__ __forceinline__ float tanhf_(float x) {
  float ax = fminf(fabsf(x), 15.f);
  float e = __builtin_amdgcn_exp2f(2.8853900817779268f * ax);
  float t = (e - 1.f) * __builtin_amdgcn_rcpf(e + 1.f);
  return copysignf(t, x);
}
// XOR swizzle within a 256-elem row
__device__ __forceinline__ int swz(int row, int col) {
  return row * 256 + ((((col >> 3) ^ (row & 7)) << 3) | (col & 7));
}
// XOR swizzle within a 512-elem row
__device__ __forceinline__ int swzK(int row, int col) {
  return row * 512 + ((((col >> 3) ^ (row & 7)) << 3) | (col & 7));
}

// ---------------- prep: weights -> bf16, transposed [verified R7/R9/R11] -----
__global__ void k_prep(const float* __restrict__ W_iou, const float* __restrict__ W_fin,
                       const float* __restrict__ W_f, const float* __restrict__ W_aggr,
                       ushort_t* __restrict__ WfT, ushort_t* __restrict__ WfinT,
                       ushort_t* __restrict__ WcatKT) {
  int tid = blockIdx.x * 256 + threadIdx.x;
  if (tid < 65536) {
    int n = tid >> 8, k = tid & 255;
    WfT[tid] = f2bf(W_f[k * 256 + n]);
  } else if (tid < 131072) {
    int t2 = tid - 65536; int n = t2 >> 8, k = t2 & 255;
    WfinT[t2] = f2bf(W_fin[k * 256 + n]);
  } else {
    int t3 = tid - 131072;            // < 393216
    int n = t3 >> 9, k = t3 & 511;
    float v = (k < 256) ? W_aggr[k * 768 + n] : W_iou[(k - 256) * 768 + n];
    WcatKT[t3] = f2bf(v);
  }
}

// ---------------- k_fin [verified R7/R9/R11] ---------------------------------
__global__ __launch_bounds__(512, 4) void k_fin(
    const float* __restrict__ x, const ushort_t* __restrict__ WfinT,
    const float* __restrict__ b_fin,
    ushort_t* __restrict__ f_out, ushort_t* __restrict__ xbf_out) {
  __shared__ __align__(16) ushort_t As[64 * 256];   // 32 KB
  const int tid = threadIdx.x;
  const size_t blk = blockIdx.x;                    // 64 rows
  const int lane = tid & 63, wv = tid >> 6;
  const int g = lane >> 4, r = lane & 15;
  const int mb = wv * 32;

  bf16x8 wfrag[2][8];
#pragma unroll
  for (int ct = 0; ct < 2; ++ct)
#pragma unroll
    for (int kb = 0; kb < 8; ++kb)
      wfrag[ct][kb] = *(const bf16x8*)&WfinT[(mb + ct * 16 + r) * 256 + kb * 32 + g * 8];
  float bias[2] = { b_fin[mb + r], b_fin[mb + 16 + r] };

  const int rowgrp = tid >> 5, seg8 = tid & 31;
  const float* src = x + ((size_t)blk * 64 + rowgrp * 4) * 256 + seg8 * 8;
#pragma unroll
  for (int rr = 0; rr < 4; ++rr) {
    float4 va = *(const float4*)(src + (size_t)rr * 256);
    float4 vb = *(const float4*)(src + (size_t)rr * 256 + 4);
    uint4 p = { cvt_pk(va.x, va.y), cvt_pk(va.z, va.w),
                cvt_pk(vb.x, vb.y), cvt_pk(vb.z, vb.w) };
    *(uint4*)&As[swz(rowgrp * 4 + rr, seg8 * 8)] = p;
    *(uint4*)&xbf_out[((size_t)blk * 64 + rowgrp * 4 + rr) * 256 + seg8 * 8] = p;
  }
  __syncthreads();

#pragma unroll
  for (int p = 0; p < 2; ++p) {
    f32x4 acc[2][2] = {};
#pragma unroll
    for (int kb = 0; kb < 8; ++kb) {
      const int kc = kb * 32 + g * 8;
      bf16x8 a0 = *(const bf16x8*)&As[swz(p * 32 + r, kc)];
      bf16x8 a1 = *(const bf16x8*)&As[swz(p * 32 + 16 + r, kc)];
      acc[0][0] = __builtin_amdgcn_mfma_f32_16x16x32_bf16(a0, wfrag[0][kb], acc[0][0], 0, 0, 0);
      acc[0][1] = __builtin_amdgcn_mfma_f32_16x16x32_bf16(a0, wfrag[1][kb], acc[0][1], 0, 0, 0);
      acc[1][0] = __builtin_amdgcn_mfma_f32_16x16x32_bf16(a1, wfrag[0][kb], acc[1][0], 0, 0, 0);
      acc[1][1] = __builtin_amdgcn_mfma_f32_16x16x32_bf16(a1, wfrag[1][kb], acc[1][1], 0, 0, 0);
    }
#pragma unroll
    for (int rt = 0; rt < 2; ++rt)
#pragma unroll
      for (int ct = 0; ct < 2; ++ct)
#pragma unroll
        for (int i = 0; i < 4; ++i) {
          float v = acc[rt][ct][i] + bias[ct];
          float v2 = __shfl_xor(v, 1);
          if ((r & 1) == 0) {
            size_t row = blk * 64 + p * 32 + rt * 16 + g * 4 + i;
            *(unsigned*)&f_out[row * 256 + mb + ct * 16 + r] = cvt_pk(v, v2);
          }
        }
  }
}

// ---------------- k_fgate v12: half-resident W, prefetch fits 64-VGPR bucket -
// R11 structure; wfrag[4] (16 regs, K-half 0 preloaded pre-barrier), second
// K-half reloaded between MFMA passes (4 L2-hot loads, once per block).
// Freed 16 regs let ncv/fvv prefetch stay resident -> epilogue latency hidden.
__global__ __launch_bounds__(1024, 4) void k_fgate(
    const float* __restrict__ nh, const float* __restrict__ nc,
    const ushort_t* __restrict__ WfT, const float* __restrict__ b_f,
    const ushort_t* __restrict__ f_in,
    float* __restrict__ cau_out, ushort_t* __restrict__ hsum_out) {
  __shared__ __align__(16) ushort_t As[64 * 256];   // 32 KB
  const int tid = threadIdx.x;
  const size_t blk = blockIdx.x;                    // 64 rows per block
  const int lane = tid & 63, wv = tid >> 6;         // wv 0..15
  const int g = lane >> 4, r = lane & 15;
  const int col = wv * 16 + r;                      // lane's output col

  // W_f^T fragments, K-half 0 only (16 VGPR), preloaded PRE-barrier
  bf16x8 wf[4];
#pragma unroll
  for (int kb = 0; kb < 4; ++kb)
    wf[kb] = *(const bf16x8*)&WfT[col * 256 + kb * 32 + g * 8];
  const float bias = b_f[col];

  // staging + fused f32 hsum: waves 0-7, wave = node, lane = col-quad
  if (wv < 8) {
    const float* src = nh + (blk * 64 + wv * 8) * 256 + lane * 4;
    float s0 = 0.f, s1 = 0.f, s2 = 0.f, s3 = 0.f;
#pragma unroll
    for (int bb = 0; bb < 2; ++bb) {
      float4 v[4];
#pragma unroll
      for (int c = 0; c < 4; ++c) v[c] = *(const float4*)(src + (size_t)(bb * 4 + c) * 256);
#pragma unroll
      for (int c = 0; c < 4; ++c) {
        uint2 p = { cvt_pk(v[c].x, v[c].y), cvt_pk(v[c].z, v[c].w) };
        *(uint2*)&As[swz(wv * 8 + bb * 4 + c, lane * 4)] = p;
        s0 += v[c].x; s1 += v[c].y; s2 += v[c].z; s3 += v[c].w;
      }
    }
    uint2 o = { cvt_pk(s0, s1), cvt_pk(s2, s3) };
    *(uint2*)&hsum_out[(blk * 8 + wv) * 256 + lane * 4] = o;
  }
  __syncthreads();

  // prefetch nc + f_in (should now stay resident in the freed registers)
  float ncv[4][4];
  float fvv[4];
#pragma unroll
  for (int rt = 0; rt < 4; ++rt) {
    const int nodeL = rt * 2 + (g >> 1);
    fvv[rt] = bf2f(f_in[(blk * 8 + nodeL) * 256 + col]);
    const float* ncp = nc + (blk * 64 + rt * 16 + g * 4) * 256 + col;
#pragma unroll
    for (int i = 0; i < 4; ++i) ncv[rt][i] = ncp[(size_t)i * 256];
  }

  // MFMA pass 0: K-half 0
  f32x4 acc[4] = {};
#pragma unroll
  for (int kb = 0; kb < 4; ++kb) {
    const int kc = kb * 32 + g * 8;
#pragma unroll
    for (int rt = 0; rt < 4; ++rt) {
      bf16x8 a = *(const bf16x8*)&As[swz(rt * 16 + r, kc)];
      acc[rt] = __builtin_amdgcn_mfma_f32_16x16x32_bf16(a, wf[kb], acc[rt], 0, 0, 0);
    }
  }
  // reload W for K-half 1 (L2-hot; WAR on wf discourages hoisting)
#pragma unroll
  for (int kb = 0; kb < 4; ++kb)
    wf[kb] = *(const bf16x8*)&WfT[col * 256 + (kb + 4) * 32 + g * 8];
  // MFMA pass 1: K-half 1
#pragma unroll
  for (int kb = 0; kb < 4; ++kb) {
    const int kc = (kb + 4) * 32 + g * 8;
#pragma unroll
    for (int rt = 0; rt < 4; ++rt) {
      bf16x8 a = *(const bf16x8*)&As[swz(rt * 16 + r, kc)];
      acc[rt] = __builtin_amdgcn_mfma_f32_16x16x32_bf16(a, wf[kb], acc[rt], 0, 0, 0);
    }
  }

  // epilogue: gates + f*nc + in-lane child reduce + 1 shfl; f32 store
#pragma unroll
  for (int rt = 0; rt < 4; ++rt) {
    const int nodeL = rt * 2 + (g >> 1);
    const size_t nodeG = blk * 8 + nodeL;
    const float base = bias + fvv[rt];
    float s = 0.f;
#pragma unroll
    for (int i = 0; i < 4; ++i)
      s += sigmoidf_(acc[rt][i] + base) * ncv[rt][i];
    s += __shfl_xor(s, 16);
    if ((g & 1) == 0)
      cau_out[nodeG * 256 + col] = s;
  }
}

// ---------------- k_final v3 [verified R11]: 64 nodes/block ------------------
// c_aggr read inline from out_c (f32, same-thread RAW only).
__global__ __launch_bounds__(512, 2) void k_final(
    const ushort_t* __restrict__ hsum, const ushort_t* __restrict__ xbf,
    const ushort_t* __restrict__ WcatKT,
    const float* __restrict__ b_iou, const float* __restrict__ b_aggr,
    float* out_h, float* out_c) {
  __shared__ __align__(16) ushort_t As[64 * 512];   // 64 KB (A = [hsum | x])
  const int tid = threadIdx.x;
  const size_t blk = blockIdx.x;                    // 64 nodes
  const int lane = tid & 63, wv = tid >> 6;
  const int g = lane >> 4, r = lane & 15;

  // stage A: 64 rows x 512 cols bf16; 8 threads/row, 8 x 16B each
  {
    int row = tid >> 3, seg = tid & 7;
    const size_t nodeG = blk * 64 + row;
#pragma unroll
    for (int jj = 0; jj < 8; ++jj) {
      int col = seg * 64 + jj * 8;
      ushort8_t v = (col < 256)
          ? *(const ushort8_t*)&hsum[nodeG * 256 + col]
          : *(const ushort8_t*)&xbf[nodeG * 256 + col - 256];
      *(ushort8_t*)&As[swzK(row, col)] = v;
    }
  }
  float biasv[3][2];
#pragma unroll
  for (int p = 0; p < 3; ++p)
#pragma unroll
    for (int j = 0; j < 2; ++j) {
      int c = p * 256 + wv * 32 + j * 16 + r;
      biasv[p][j] = b_iou[c] + b_aggr[c];
    }
  __syncthreads();

  f32x4 acc[3][4][2] = {};   // [p][rt][j]  (96 VGPR)
#pragma unroll
  for (int q = 0; q < 8; ++q) {
    bf16x8 wf[3][2][2];
#pragma unroll
    for (int p = 0; p < 3; ++p)
#pragma unroll
      for (int j = 0; j < 2; ++j)
#pragma unroll
        for (int kb = 0; kb < 2; ++kb)
          wf[p][j][kb] = *(const bf16x8*)&WcatKT[
              (size_t)(p * 256 + wv * 32 + j * 16 + r) * 512 + q * 64 + kb * 32 + g * 8];
#pragma unroll
    for (int kb = 0; kb < 2; ++kb) {
      const int kc = q * 64 + kb * 32 + g * 8;
#pragma unroll
      for (int rt = 0; rt < 4; ++rt) {
        bf16x8 a = *(const bf16x8*)&As[swzK(rt * 16 + r, kc)];
#pragma unroll
        for (int p = 0; p < 3; ++p)
#pragma unroll
          for (int j = 0; j < 2; ++j)
            acc[p][rt][j] = __builtin_amdgcn_mfma_f32_16x16x32_bf16(a, wf[p][j][kb], acc[p][rt][j], 0, 0, 0);
      }
    }
  }

#pragma unroll
  for (int rt = 0; rt < 4; ++rt)
#pragma unroll
    for (int j = 0; j < 2; ++j)
#pragma unroll
      for (int i = 0; i < 4; ++i) {
        int nl = rt * 16 + g * 4 + i;
        int col = wv * 32 + j * 16 + r;
        size_t node = blk * 64 + nl;
        float iv = acc[0][rt][j][i] + biasv[0][j];
        float ov = acc[1][rt][j][i] + biasv[1][j];
        float uv = acc[2][rt][j][i] + biasv[2][j];
        float ca = out_c[node * 256 + col];          // f32 c_aggr (same thread)
        float cn = sigmoidf_(iv) * tanhf_(uv) + ca;
        out_c[node * 256 + col] = cn;
        out_h[node * 256 + col] = sigmoidf_(ov) * tanhf_(cn);
      }
}

extern "C" void kernel_launch(void* const* d_in, const int* in_sizes, int n_in,
                              void* d_out, int out_size, void* d_ws, size_t ws_size,
                              hipStream_t stream) {
  const float* x      = (const float*)d_in[0];
  const float* nh     = (const float*)d_in[1];
  const float* nc     = (const float*)d_in[2];
  const float* W_iou  = (const float*)d_in[3];
  const float* b_iou  = (const float*)d_in[4];
  const float* W_fin  = (const float*)d_in[5];
  const float* b_fin  = (const float*)d_in[6];
  const float* W_f    = (const float*)d_in[7];
  const float* b_f    = (const float*)d_in[8];
  const float* W_aggr = (const float*)d_in[9];
  const float* b_aggr = (const float*)d_in[10];

  char* ws = (char*)d_ws;
  ushort_t* WfT    = (ushort_t*)ws;                               // 128 KB
  ushort_t* WfinT  = (ushort_t*)(ws + (128 << 10));               // 128 KB
  ushort_t* WcatKT = (ushort_t*)(ws + (256 << 10));               // 768 KB
  ushort_t* f_in   = (ushort_t*)(ws + (1 << 20));                 // 16 MB
  ushort_t* hsum   = (ushort_t*)(ws + (17 << 20));                // 16 MB
  ushort_t* x_bf   = (ushort_t*)(ws + (33 << 20));                // 16 MB

  float* out_h = (float*)d_out;
  float* out_c = out_h + (size_t)NN * HH;

  k_prep<<<2048, 256, 0, stream>>>(W_iou, W_fin, W_f, W_aggr, WfT, WfinT, WcatKT);
  k_fin<<<512, 512, 0, stream>>>(x, WfinT, b_fin, f_in, x_bf);
  k_fgate<<<4096, 1024, 0, stream>>>(nh, nc, WfT, b_f, f_in, out_c, hsum);
  k_final<<<512, 512, 0, stream>>>(hsum, x_bf, WcatKT, b_iou, b_aggr, out_h, out_c);
}